// Round 10
// baseline (475.413 us; speedup 1.0000x reference)
//
#include <hip/hip_runtime.h>
#include <hip/hip_bf16.h>
#include <math.h>

// Problem constants
#define S 2048
#define H 1024
#define NE 8
#define INTER 2048
#define ALPHA 1.702f
#define LIMIT 7.0f

typedef __bf16 bf16x8 __attribute__((ext_vector_type(8)));
typedef float f32x4 __attribute__((ext_vector_type(4)));
typedef unsigned short u16x8 __attribute__((ext_vector_type(8)));

// Workspace layout (bytes)
#define WS_COUNTS 0                                   // 4 KB
#define WS_SLOTS  4096                                // int[NE][S] = 64 KB
#define WS_W      (WS_SLOTS + NE*S*4)                 // float[2S] = 16 KB
#define WS_XB     (WS_W + 2*S*4)                      // bf16 x [S][H] = 4 MB
#define WS_GUP    (WS_XB + (size_t)S*H*2)             // bf16 [E][H/32][2I][32] = 64 MB
#define WS_DPN    (WS_GUP + (size_t)NE*2*INTER*H*2)   // bf16 [E][I/32][H][32] = 32 MB
#define WS_ACT    (WS_DPN + (size_t)NE*H*INTER*2)     // bf16 [2S][I] = 16 MB

static __device__ __forceinline__ unsigned short f2bf(float f) {
    union { __hip_bfloat16 h; unsigned short u; } cv;
    cv.h = __float2bfloat16(f);
    return cv.u;
}

static __device__ __forceinline__ void gload16(const void* g, void* l) {
    __builtin_amdgcn_global_load_lds(
        (const __attribute__((address_space(1))) unsigned int*)(unsigned long long)g,
        (__attribute__((address_space(3))) unsigned int*)(unsigned int)(unsigned long long)l,
        16, 0, 0);
}

// LDS-only barrier (no vmcnt drain): prefetch global loads stay in flight.
static __device__ __forceinline__ void ldsbar() {
    asm volatile("s_waitcnt lgkmcnt(0)" ::: "memory");
    __builtin_amdgcn_s_barrier();
}

// ---------------------------------------------------------------------------
// Router + x->bf16 conversion. One wave per token.
// ---------------------------------------------------------------------------
__global__ __launch_bounds__(64) void router_conv(
    const float* __restrict__ x, const float* __restrict__ rw,
    const float* __restrict__ rb, int* __restrict__ counts,
    int* __restrict__ slots, float* __restrict__ slot_w,
    unsigned short* __restrict__ xb)
{
    int tok = blockIdx.x;
    int lane = threadIdx.x;
    const float4* xr = (const float4*)(x + (size_t)tok * H);
    ushort4* xo = (ushort4*)(xb + (size_t)tok * H);
    float acc[NE];
#pragma unroll
    for (int e = 0; e < NE; ++e) acc[e] = 0.f;
#pragma unroll
    for (int p = 0; p < H / 256; ++p) {
        int idx = p * 64 + lane;
        float4 v = xr[idx];
        ushort4 o;
        o.x = f2bf(v.x); o.y = f2bf(v.y); o.z = f2bf(v.z); o.w = f2bf(v.w);
        xo[idx] = o;
        const float* wr = rw + (size_t)idx * 4 * NE;
#pragma unroll
        for (int e = 0; e < NE; ++e)
            acc[e] += v.x * wr[e] + v.y * wr[NE + e] + v.z * wr[2 * NE + e] + v.w * wr[3 * NE + e];
    }
#pragma unroll
    for (int e = 0; e < NE; ++e) {
#pragma unroll
        for (int off = 32; off > 0; off >>= 1)
            acc[e] += __shfl_down(acc[e], off);
    }
    if (lane == 0) {
        float v[NE];
#pragma unroll
        for (int e = 0; e < NE; ++e) v[e] = acc[e] + rb[e];
        int i1 = 0; float v1 = v[0];
#pragma unroll
        for (int e = 1; e < NE; ++e) if (v[e] > v1) { v1 = v[e]; i1 = e; }
        int i2 = -1; float v2 = -3.0e38f;
#pragma unroll
        for (int e = 0; e < NE; ++e) if (e != i1 && v[e] > v2) { v2 = v[e]; i2 = e; }
        float w1 = 1.f / (1.f + expf(v2 - v1));
        float w2 = 1.f - w1;
        int p1 = atomicAdd(&counts[i1], 1);
        slots[i1 * S + p1] = tok * 2;
        slot_w[tok * 2] = w1;
        int p2 = atomicAdd(&counts[i2], 1);
        slots[i2 * S + p2] = tok * 2 + 1;
        slot_w[tok * 2 + 1] = w2;
    }
}

// ---------------------------------------------------------------------------
// Streaming weight repack: fp32 [K][W] rows -> bf16 k-blocked [K/32][W][32].
// The [N][K] transpose target of rounds 0-9 forced strided IO on one side
// (256-B read chunks @16KB stride, 128-B write chunks @2-4KB stride) -- the
// measured ~95us floor that survived conflict/pipeline fixes. k-blocked
// layout gives the GEMM identical gload16 consumption (only address math
// changes) while prep becomes pure streaming: each block owns 32 full input
// rows (32 sequential read streams) and ONE sequential write stream
// (1KB/wave, 4KB/chunk contiguous).
// Per 64-col chunk: stage fp32 [32][65] in LDS (write banks (k+n)%32: 2-way;
// transpose-read banks (rk+i+rn)%32: 2-way -- both free), cvt on read.
// Reg double-buffer + ldsbar keeps next chunk's loads in flight.
// grid: NE*32 gate/up blocks + NE*64 down blocks = 768, 256 thr.
// ---------------------------------------------------------------------------
__global__ __launch_bounds__(256) void prep(
    const float* __restrict__ gup, const float* __restrict__ dp,
    unsigned short* __restrict__ gw, unsigned short* __restrict__ dw)
{
    int b = blockIdx.x;
    const float* in;
    unsigned short* out;
    int W, NC;
    if (b < NE * 32) {                    // gate+up: rows of gup[e], W = 2*INTER
        int e = b >> 5, kb = b & 31;
        in  = gup + ((size_t)e * H + kb * 32) * (2 * INTER);
        out = gw  + (size_t)e * 2 * INTER * H + (size_t)kb * 2 * INTER * 32;
        W = 2 * INTER; NC = (2 * INTER) / 64;
    } else {                              // down: rows of dp[e], W = H
        int bb = b - NE * 32;
        int e = bb >> 6, kb = bb & 63;
        in  = dp + ((size_t)e * INTER + kb * 32) * H;
        out = dw + (size_t)e * INTER * H + (size_t)kb * H * 32;
        W = H; NC = H / 64;
    }

    __shared__ float tile[32][65];
    int t = threadIdx.x;
    int lk = t >> 3, ln = (t & 7) * 8;    // load: row lk (0..31), cols ln..ln+7
    int rn = t >> 2, rk = (t & 3) * 8;    // emit: out-row rn (0..63), k rk..rk+7

    const float* src = in + (size_t)lk * W + ln;
    float4 a0, a1, b0, b1;
    a0 = *(const float4*)(src);       a1 = *(const float4*)(src + 4);
    b0 = *(const float4*)(src + 64);  b1 = *(const float4*)(src + 68);

    for (int nc = 0; nc < NC; nc += 2) {
        // chunk nc (bufA)
        *(f32x4*)&tile[lk][ln]     = (f32x4){a0.x, a0.y, a0.z, a0.w};
        *(f32x4*)&tile[lk][ln + 4] = (f32x4){a1.x, a1.y, a1.z, a1.w};
        if (nc + 2 < NC) {
            const float* s = src + (size_t)(nc + 2) * 64;
            a0 = *(const float4*)(s); a1 = *(const float4*)(s + 4);
        }
        ldsbar();
        {
            u16x8 o;
#pragma unroll
            for (int i = 0; i < 8; ++i) o[i] = f2bf(tile[rk + i][rn]);
            *(u16x8*)(out + (size_t)(nc * 64 + rn) * 32 + rk) = o;
        }
        ldsbar();
        // chunk nc+1 (bufB)
        *(f32x4*)&tile[lk][ln]     = (f32x4){b0.x, b0.y, b0.z, b0.w};
        *(f32x4*)&tile[lk][ln + 4] = (f32x4){b1.x, b1.y, b1.z, b1.w};
        if (nc + 3 < NC) {
            const float* s = src + (size_t)(nc + 3) * 64;
            b0 = *(const float4*)(s); b1 = *(const float4*)(s + 4);
        }
        ldsbar();
        {
            u16x8 o;
#pragma unroll
            for (int i = 0; i < 8; ++i) o[i] = f2bf(tile[rk + i][rn]);
            *(u16x8*)(out + (size_t)((nc + 1) * 64 + rn) * 32 + rk) = o;
        }
        ldsbar();
    }
}

// ---------------------------------------------------------------------------
// Grouped gate_up MFMA GEMM + fused activation -> act (bf16).
// Tile M=128 x N=64 (gate+up together), BK=32, 4 waves 2x2.
// B layout: k-blocked gw[e][H/32][2I][32] -- k-tile kb at offset k0*2*INTER.
// ---------------------------------------------------------------------------
__global__ __launch_bounds__(256) void gateup_mfma(
    const unsigned short* __restrict__ xb,
    const unsigned short* __restrict__ gw,
    const float* __restrict__ gub,
    const int* __restrict__ counts, const int* __restrict__ slots,
    unsigned short* __restrict__ act)
{
    int e = blockIdx.z;
    int cnt = counts[e];
    int m0 = blockIdx.y * 128;
    if (m0 >= cnt) return;
    int n0 = blockIdx.x * 64;

    __shared__ unsigned short As[128 * 32];
    __shared__ unsigned short Gs[64 * 32];
    __shared__ unsigned short Us[64 * 32];
    __shared__ int sl[128];

    int t = threadIdx.x;
    int lane = t & 63, w = t >> 6;
    if (t < 128) {
        int r = m0 + t;
        sl[t] = slots[e * S + (r < cnt ? r : cnt - 1)];
    }
    __syncthreads();

    int quad = lane >> 4, l16 = lane & 15;
    int wm = (w >> 1) * 64, wn = (w & 1) * 32;

    int ar0 = w * 32 + (lane >> 2);
    int ar1 = ar0 + 16;
    const unsigned short* ap0 = xb + (size_t)(sl[ar0] >> 1) * H + (lane & 3) * 8;
    const unsigned short* ap1 = xb + (size_t)(sl[ar1] >> 1) * H + (lane & 3) * 8;
    int bn = w * 16 + (lane >> 2);
    // k-blocked layout: [e][kb][nn][32]; per-k-tile offset = k0*2*INTER shorts
    const unsigned short* gp = gw + (size_t)e * 2 * INTER * H + (size_t)(n0 + bn) * 32 + (lane & 3) * 8;
    const unsigned short* up = gp + (size_t)INTER * 32;

    unsigned short* la0 = &As[(2 * w) * 512 + lane * 8];
    unsigned short* la1 = &As[(2 * w + 1) * 512 + lane * 8];
    unsigned short* lg = &Gs[w * 512 + lane * 8];
    unsigned short* lu = &Us[w * 512 + lane * 8];

    f32x4 accg[4][2], accu[4][2];
#pragma unroll
    for (int mi = 0; mi < 4; ++mi)
#pragma unroll
        for (int ni = 0; ni < 2; ++ni) {
            accg[mi][ni] = (f32x4){0.f, 0.f, 0.f, 0.f};
            accu[mi][ni] = (f32x4){0.f, 0.f, 0.f, 0.f};
        }

    for (int k0 = 0; k0 < H; k0 += 32) {
        __syncthreads();
        gload16(ap0 + k0, la0);
        gload16(ap1 + k0, la1);
        gload16(gp + (size_t)k0 * 2 * INTER, lg);
        gload16(up + (size_t)k0 * 2 * INTER, lu);
        __syncthreads();
        bf16x8 af[4], gf[2], uf[2];
#pragma unroll
        for (int mi = 0; mi < 4; ++mi)
            af[mi] = *(const bf16x8*)&As[(wm + mi * 16 + l16) * 32 + quad * 8];
#pragma unroll
        for (int ni = 0; ni < 2; ++ni) {
            gf[ni] = *(const bf16x8*)&Gs[(wn + ni * 16 + l16) * 32 + quad * 8];
            uf[ni] = *(const bf16x8*)&Us[(wn + ni * 16 + l16) * 32 + quad * 8];
        }
#pragma unroll
        for (int mi = 0; mi < 4; ++mi)
#pragma unroll
            for (int ni = 0; ni < 2; ++ni) {
                accg[mi][ni] = __builtin_amdgcn_mfma_f32_16x16x32_bf16(af[mi], gf[ni], accg[mi][ni], 0, 0, 0);
                accu[mi][ni] = __builtin_amdgcn_mfma_f32_16x16x32_bf16(af[mi], uf[ni], accu[mi][ni], 0, 0, 0);
            }
    }

    const float* gb = gub + (size_t)e * 2 * INTER;
#pragma unroll
    for (int mi = 0; mi < 4; ++mi) {
#pragma unroll
        for (int r = 0; r < 4; ++r) {
            int rt = wm + mi * 16 + quad * 4 + r;
            if (m0 + rt >= cnt) continue;
            int slot = sl[rt];
            unsigned short* orow = act + (size_t)slot * INTER;
#pragma unroll
            for (int ni = 0; ni < 2; ++ni) {
                int col = n0 + wn + ni * 16 + l16;
                float gate = accg[mi][ni][r] + gb[col];
                float uv = accu[mi][ni][r] + gb[INTER + col];
                gate = fminf(gate, LIMIT);
                uv = fminf(fmaxf(uv, -LIMIT), LIMIT);
                float glu = gate / (1.f + __expf(-ALPHA * gate));
                orow[col] = f2bf((uv + 1.f) * glu);
            }
        }
    }
}

// ---------------------------------------------------------------------------
// Grouped down MFMA GEMM + bias + weighted combine. K-split 2.
// B layout: k-blocked dw[e][I/32][H][32] -- per-k-tile offset = k0*H shorts.
// ---------------------------------------------------------------------------
__global__ __launch_bounds__(256) void down_mfma(
    const unsigned short* __restrict__ act,
    const unsigned short* __restrict__ dw,
    const float* __restrict__ db,
    const int* __restrict__ counts, const int* __restrict__ slots,
    const float* __restrict__ slot_w,
    float* __restrict__ out)
{
    int e = blockIdx.z >> 1;
    int ks = blockIdx.z & 1;
    int cnt = counts[e];
    int m0 = blockIdx.y * 128;
    if (m0 >= cnt) return;
    int n0 = blockIdx.x * 64;

    __shared__ unsigned short As[128 * 32];
    __shared__ unsigned short Bs[64 * 32];
    __shared__ int sl[128];

    int t = threadIdx.x;
    int lane = t & 63, w = t >> 6;
    if (t < 128) {
        int r = m0 + t;
        sl[t] = slots[e * S + (r < cnt ? r : cnt - 1)];
    }
    __syncthreads();

    int quad = lane >> 4, l16 = lane & 15;
    int wm = (w >> 1) * 64, wn = (w & 1) * 32;

    int ar0 = w * 32 + (lane >> 2);
    int ar1 = ar0 + 16;
    int kbase = ks * (INTER / 2);
    const unsigned short* ap0 = act + (size_t)sl[ar0] * INTER + kbase + (lane & 3) * 8;
    const unsigned short* ap1 = act + (size_t)sl[ar1] * INTER + kbase + (lane & 3) * 8;
    int bn = w * 16 + (lane >> 2);
    // k-blocked: [e][kb][n][32]; start at kb = kbase/32 -> offset kbase*H
    const unsigned short* bp = dw + (size_t)e * H * INTER + (size_t)kbase * H + (size_t)(n0 + bn) * 32 + (lane & 3) * 8;

    unsigned short* la0 = &As[(2 * w) * 512 + lane * 8];
    unsigned short* la1 = &As[(2 * w + 1) * 512 + lane * 8];
    unsigned short* lb = &Bs[w * 512 + lane * 8];

    f32x4 acc[4][2];
#pragma unroll
    for (int mi = 0; mi < 4; ++mi)
#pragma unroll
        for (int ni = 0; ni < 2; ++ni)
            acc[mi][ni] = (f32x4){0.f, 0.f, 0.f, 0.f};

    for (int k0 = 0; k0 < INTER / 2; k0 += 32) {
        __syncthreads();
        gload16(ap0 + k0, la0);
        gload16(ap1 + k0, la1);
        gload16(bp + (size_t)k0 * H, lb);
        __syncthreads();
        bf16x8 af[4], bf[2];
#pragma unroll
        for (int mi = 0; mi < 4; ++mi)
            af[mi] = *(const bf16x8*)&As[(wm + mi * 16 + l16) * 32 + quad * 8];
#pragma unroll
        for (int ni = 0; ni < 2; ++ni)
            bf[ni] = *(const bf16x8*)&Bs[(wn + ni * 16 + l16) * 32 + quad * 8];
#pragma unroll
        for (int mi = 0; mi < 4; ++mi)
#pragma unroll
            for (int ni = 0; ni < 2; ++ni)
                acc[mi][ni] = __builtin_amdgcn_mfma_f32_16x16x32_bf16(af[mi], bf[ni], acc[mi][ni], 0, 0, 0);
    }

    const float* dbr = db + (size_t)e * H;
#pragma unroll
    for (int mi = 0; mi < 4; ++mi) {
#pragma unroll
        for (int r = 0; r < 4; ++r) {
            int rt = wm + mi * 16 + quad * 4 + r;
            if (m0 + rt >= cnt) continue;
            int slot = sl[rt];
            int tok = slot >> 1;
            float wgt = slot_w[slot];
#pragma unroll
            for (int ni = 0; ni < 2; ++ni) {
                int col = n0 + wn + ni * 16 + l16;
                float rr = acc[mi][ni][r] + (ks == 0 ? dbr[col] : 0.f);
                atomicAdd(&out[(size_t)tok * H + col], wgt * rr);
            }
        }
    }
}

// ---------------------------------------------------------------------------
extern "C" void kernel_launch(void* const* d_in, const int* in_sizes, int n_in,
                              void* d_out, int out_size, void* d_ws, size_t ws_size,
                              hipStream_t stream)
{
    const float* x   = (const float*)d_in[0];
    const float* rw  = (const float*)d_in[1];
    const float* rb  = (const float*)d_in[2];
    const float* gup = (const float*)d_in[3];
    const float* gub = (const float*)d_in[4];
    const float* dp  = (const float*)d_in[5];
    const float* db  = (const float*)d_in[6];
    float* out = (float*)d_out;

    char* ws = (char*)d_ws;
    int* counts            = (int*)(ws + WS_COUNTS);
    int* slots             = (int*)(ws + WS_SLOTS);
    float* slot_w          = (float*)(ws + WS_W);
    unsigned short* xb     = (unsigned short*)(ws + WS_XB);
    unsigned short* gw     = (unsigned short*)(ws + WS_GUP);
    unsigned short* dw     = (unsigned short*)(ws + WS_DPN);
    unsigned short* act    = (unsigned short*)(ws + WS_ACT);

    hipMemsetAsync(counts, 0, 4096, stream);
    hipMemsetAsync(out, 0, (size_t)S * H * sizeof(float), stream);

    router_conv<<<S, 64, 0, stream>>>(x, rw, rb, counts, slots, slot_w, xb);

    // streaming repack: 256 gate/up blocks (32 rows x 4096) + 512 down blocks
    prep<<<NE * 32 + NE * 64, 256, 0, stream>>>(gup, dp, gw, dw);

    gateup_mfma<<<dim3(INTER / 64, 16, NE), 256, 0, stream>>>(
        xb, gw, gub, counts, slots, act);

    down_mfma<<<dim3(H / 64, 16, NE * 2), 256, 0, stream>>>(
        act, dw, db, counts, slots, slot_w, out);
}

// Round 14
// 459.384 us; speedup vs baseline: 1.0349x; 1.0349x over previous
//
#include <hip/hip_runtime.h>
#include <hip/hip_bf16.h>
#include <math.h>

// Problem constants
#define S 2048
#define H 1024
#define NE 8
#define INTER 2048
#define ALPHA 1.702f
#define LIMIT 7.0f

typedef __bf16 bf16x8 __attribute__((ext_vector_type(8)));
typedef float f32x4 __attribute__((ext_vector_type(4)));
typedef unsigned short u16x8 __attribute__((ext_vector_type(8)));

// Workspace layout (bytes)
#define WS_COUNTS 0                                   // 4 KB
#define WS_SLOTS  4096                                // int[NE][S] = 64 KB
#define WS_W      (WS_SLOTS + NE*S*4)                 // float[2S] = 16 KB
#define WS_XB     (WS_W + 2*S*4)                      // bf16 x [S][H] = 4 MB
#define WS_GUP    (WS_XB + (size_t)S*H*2)             // bf16 [E][H/32][2I][32] = 64 MB
#define WS_DPN    (WS_GUP + (size_t)NE*2*INTER*H*2)   // bf16 [E][I/32][H][32] = 32 MB
#define WS_ACT    (WS_DPN + (size_t)NE*H*INTER*2)     // bf16 [2S][I] = 16 MB

static __device__ __forceinline__ unsigned short f2bf(float f) {
    union { __hip_bfloat16 h; unsigned short u; } cv;
    cv.h = __float2bfloat16(f);
    return cv.u;
}

static __device__ __forceinline__ void gload16(const void* g, void* l) {
    __builtin_amdgcn_global_load_lds(
        (const __attribute__((address_space(1))) unsigned int*)(unsigned long long)g,
        (__attribute__((address_space(3))) unsigned int*)(unsigned int)(unsigned long long)l,
        16, 0, 0);
}

// LDS-only barrier (no vmcnt drain): prefetch global loads stay in flight.
static __device__ __forceinline__ void ldsbar() {
    asm volatile("s_waitcnt lgkmcnt(0)" ::: "memory");
    __builtin_amdgcn_s_barrier();
}

// ---------------------------------------------------------------------------
// Router + x->bf16 conversion. One wave per token.
// ---------------------------------------------------------------------------
__global__ __launch_bounds__(64) void router_conv(
    const float* __restrict__ x, const float* __restrict__ rw,
    const float* __restrict__ rb, int* __restrict__ counts,
    int* __restrict__ slots, float* __restrict__ slot_w,
    unsigned short* __restrict__ xb)
{
    int tok = blockIdx.x;
    int lane = threadIdx.x;
    const float4* xr = (const float4*)(x + (size_t)tok * H);
    ushort4* xo = (ushort4*)(xb + (size_t)tok * H);
    float acc[NE];
#pragma unroll
    for (int e = 0; e < NE; ++e) acc[e] = 0.f;
#pragma unroll
    for (int p = 0; p < H / 256; ++p) {
        int idx = p * 64 + lane;
        float4 v = xr[idx];
        ushort4 o;
        o.x = f2bf(v.x); o.y = f2bf(v.y); o.z = f2bf(v.z); o.w = f2bf(v.w);
        xo[idx] = o;
        const float* wr = rw + (size_t)idx * 4 * NE;
#pragma unroll
        for (int e = 0; e < NE; ++e)
            acc[e] += v.x * wr[e] + v.y * wr[NE + e] + v.z * wr[2 * NE + e] + v.w * wr[3 * NE + e];
    }
#pragma unroll
    for (int e = 0; e < NE; ++e) {
#pragma unroll
        for (int off = 32; off > 0; off >>= 1)
            acc[e] += __shfl_down(acc[e], off);
    }
    if (lane == 0) {
        float v[NE];
#pragma unroll
        for (int e = 0; e < NE; ++e) v[e] = acc[e] + rb[e];
        int i1 = 0; float v1 = v[0];
#pragma unroll
        for (int e = 1; e < NE; ++e) if (v[e] > v1) { v1 = v[e]; i1 = e; }
        int i2 = -1; float v2 = -3.0e38f;
#pragma unroll
        for (int e = 0; e < NE; ++e) if (e != i1 && v[e] > v2) { v2 = v[e]; i2 = e; }
        float w1 = 1.f / (1.f + expf(v2 - v1));
        float w2 = 1.f - w1;
        int p1 = atomicAdd(&counts[i1], 1);
        slots[i1 * S + p1] = tok * 2;
        slot_w[tok * 2] = w1;
        int p2 = atomicAdd(&counts[i2], 1);
        slots[i2 * S + p2] = tok * 2 + 1;
        slot_w[tok * 2 + 1] = w2;
    }
}

// ---------------------------------------------------------------------------
// Streaming weight repack: fp32 [K][W] rows -> bf16 k-blocked [K/32][W][32].
// Round-10 showed streaming IO at 20% occupancy (768 blocks, 4:1 imbalance)
// -> grid starvation, 1.7 TB/s. Fix: 1536 EQUAL blocks, each owns a
// 32k x 1024col chunk (128 KB read / 64 KB write, NC=16 inner 64-col steps).
// gate/up: 8e x 32kb x 4colchunk = 1024 blocks; down: 8e x 64kb = 512.
// 6 blocks/CU, zero tail imbalance. Reads: 32 sequential row streams/block;
// writes: one sequential stream. LDS fp32 [32][65]: both phases 2-way (free).
// Reg double-buffer + ldsbar keeps next chunk's loads in flight.
// ---------------------------------------------------------------------------
__global__ __launch_bounds__(256) void prep(
    const float* __restrict__ gup, const float* __restrict__ dp,
    unsigned short* __restrict__ gw, unsigned short* __restrict__ dw)
{
    int b = blockIdx.x;
    const float* in;
    unsigned short* out;
    int rowstride;
    if (b < NE * 128) {                   // gate+up: [e][kb*32+k][wc*1024+n]
        int e = b >> 7, r = b & 127;
        int kb = r >> 2, wc = r & 3;
        in  = gup + ((size_t)e * H + kb * 32) * (2 * INTER) + wc * 1024;
        out = gw  + (size_t)e * 2 * INTER * H + (size_t)kb * 2 * INTER * 32
                  + (size_t)wc * 1024 * 32;
        rowstride = 2 * INTER;
    } else {                              // down: [e][kb*32+k][n], W = H = 1024
        int bb = b - NE * 128;
        int e = bb >> 6, kb = bb & 63;
        in  = dp + ((size_t)e * INTER + kb * 32) * H;
        out = dw + (size_t)e * INTER * H + (size_t)kb * H * 32;
        rowstride = H;
    }
    const int NC = 16;                    // 16 x 64 cols = 1024 cols per block

    __shared__ float tile[32][65];
    int t = threadIdx.x;
    int lk = t >> 3, ln = (t & 7) * 8;    // load: row lk (0..31), cols ln..ln+7
    int rn = t >> 2, rk = (t & 3) * 8;    // emit: out-row rn (0..63), k rk..rk+7

    const float* src = in + (size_t)lk * rowstride + ln;
    float4 a0, a1, b0, b1;
    a0 = *(const float4*)(src);       a1 = *(const float4*)(src + 4);
    b0 = *(const float4*)(src + 64);  b1 = *(const float4*)(src + 68);

    for (int nc = 0; nc < NC; nc += 2) {
        // chunk nc (bufA)
        *(f32x4*)&tile[lk][ln]     = (f32x4){a0.x, a0.y, a0.z, a0.w};
        *(f32x4*)&tile[lk][ln + 4] = (f32x4){a1.x, a1.y, a1.z, a1.w};
        if (nc + 2 < NC) {
            const float* s = src + (size_t)(nc + 2) * 64;
            a0 = *(const float4*)(s); a1 = *(const float4*)(s + 4);
        }
        ldsbar();
        {
            u16x8 o;
#pragma unroll
            for (int i = 0; i < 8; ++i) o[i] = f2bf(tile[rk + i][rn]);
            *(u16x8*)(out + (size_t)(nc * 64 + rn) * 32 + rk) = o;
        }
        ldsbar();
        // chunk nc+1 (bufB)
        *(f32x4*)&tile[lk][ln]     = (f32x4){b0.x, b0.y, b0.z, b0.w};
        *(f32x4*)&tile[lk][ln + 4] = (f32x4){b1.x, b1.y, b1.z, b1.w};
        if (nc + 3 < NC) {
            const float* s = src + (size_t)(nc + 3) * 64;
            b0 = *(const float4*)(s); b1 = *(const float4*)(s + 4);
        }
        ldsbar();
        {
            u16x8 o;
#pragma unroll
            for (int i = 0; i < 8; ++i) o[i] = f2bf(tile[rk + i][rn]);
            *(u16x8*)(out + (size_t)((nc + 1) * 64 + rn) * 32 + rk) = o;
        }
        ldsbar();
    }
}

// ---------------------------------------------------------------------------
// Grouped gate_up MFMA GEMM + fused activation -> act (bf16).
// Tile M=128 x N=64 (gate+up together), BK=32, 4 waves 2x2.
// B layout: k-blocked gw[e][H/32][2I][32] -- k-tile kb at offset k0*2*INTER.
// ---------------------------------------------------------------------------
__global__ __launch_bounds__(256) void gateup_mfma(
    const unsigned short* __restrict__ xb,
    const unsigned short* __restrict__ gw,
    const float* __restrict__ gub,
    const int* __restrict__ counts, const int* __restrict__ slots,
    unsigned short* __restrict__ act)
{
    int e = blockIdx.z;
    int cnt = counts[e];
    int m0 = blockIdx.y * 128;
    if (m0 >= cnt) return;
    int n0 = blockIdx.x * 64;

    __shared__ unsigned short As[128 * 32];
    __shared__ unsigned short Gs[64 * 32];
    __shared__ unsigned short Us[64 * 32];
    __shared__ int sl[128];

    int t = threadIdx.x;
    int lane = t & 63, w = t >> 6;
    if (t < 128) {
        int r = m0 + t;
        sl[t] = slots[e * S + (r < cnt ? r : cnt - 1)];
    }
    __syncthreads();

    int quad = lane >> 4, l16 = lane & 15;
    int wm = (w >> 1) * 64, wn = (w & 1) * 32;

    int ar0 = w * 32 + (lane >> 2);
    int ar1 = ar0 + 16;
    const unsigned short* ap0 = xb + (size_t)(sl[ar0] >> 1) * H + (lane & 3) * 8;
    const unsigned short* ap1 = xb + (size_t)(sl[ar1] >> 1) * H + (lane & 3) * 8;
    int bn = w * 16 + (lane >> 2);
    // k-blocked layout: [e][kb][nn][32]; per-k-tile offset = k0*2*INTER shorts
    const unsigned short* gp = gw + (size_t)e * 2 * INTER * H + (size_t)(n0 + bn) * 32 + (lane & 3) * 8;
    const unsigned short* up = gp + (size_t)INTER * 32;

    unsigned short* la0 = &As[(2 * w) * 512 + lane * 8];
    unsigned short* la1 = &As[(2 * w + 1) * 512 + lane * 8];
    unsigned short* lg = &Gs[w * 512 + lane * 8];
    unsigned short* lu = &Us[w * 512 + lane * 8];

    f32x4 accg[4][2], accu[4][2];
#pragma unroll
    for (int mi = 0; mi < 4; ++mi)
#pragma unroll
        for (int ni = 0; ni < 2; ++ni) {
            accg[mi][ni] = (f32x4){0.f, 0.f, 0.f, 0.f};
            accu[mi][ni] = (f32x4){0.f, 0.f, 0.f, 0.f};
        }

    for (int k0 = 0; k0 < H; k0 += 32) {
        __syncthreads();
        gload16(ap0 + k0, la0);
        gload16(ap1 + k0, la1);
        gload16(gp + (size_t)k0 * 2 * INTER, lg);
        gload16(up + (size_t)k0 * 2 * INTER, lu);
        __syncthreads();
        bf16x8 af[4], gf[2], uf[2];
#pragma unroll
        for (int mi = 0; mi < 4; ++mi)
            af[mi] = *(const bf16x8*)&As[(wm + mi * 16 + l16) * 32 + quad * 8];
#pragma unroll
        for (int ni = 0; ni < 2; ++ni) {
            gf[ni] = *(const bf16x8*)&Gs[(wn + ni * 16 + l16) * 32 + quad * 8];
            uf[ni] = *(const bf16x8*)&Us[(wn + ni * 16 + l16) * 32 + quad * 8];
        }
#pragma unroll
        for (int mi = 0; mi < 4; ++mi)
#pragma unroll
            for (int ni = 0; ni < 2; ++ni) {
                accg[mi][ni] = __builtin_amdgcn_mfma_f32_16x16x32_bf16(af[mi], gf[ni], accg[mi][ni], 0, 0, 0);
                accu[mi][ni] = __builtin_amdgcn_mfma_f32_16x16x32_bf16(af[mi], uf[ni], accu[mi][ni], 0, 0, 0);
            }
    }

    const float* gb = gub + (size_t)e * 2 * INTER;
#pragma unroll
    for (int mi = 0; mi < 4; ++mi) {
#pragma unroll
        for (int r = 0; r < 4; ++r) {
            int rt = wm + mi * 16 + quad * 4 + r;
            if (m0 + rt >= cnt) continue;
            int slot = sl[rt];
            unsigned short* orow = act + (size_t)slot * INTER;
#pragma unroll
            for (int ni = 0; ni < 2; ++ni) {
                int col = n0 + wn + ni * 16 + l16;
                float gate = accg[mi][ni][r] + gb[col];
                float uv = accu[mi][ni][r] + gb[INTER + col];
                gate = fminf(gate, LIMIT);
                uv = fminf(fmaxf(uv, -LIMIT), LIMIT);
                float glu = gate / (1.f + __expf(-ALPHA * gate));
                orow[col] = f2bf((uv + 1.f) * glu);
            }
        }
    }
}

// ---------------------------------------------------------------------------
// Grouped down MFMA GEMM + bias + weighted combine. K-split 2.
// B layout: k-blocked dw[e][I/32][H][32] -- per-k-tile offset = k0*H shorts.
// ---------------------------------------------------------------------------
__global__ __launch_bounds__(256) void down_mfma(
    const unsigned short* __restrict__ act,
    const unsigned short* __restrict__ dw,
    const float* __restrict__ db,
    const int* __restrict__ counts, const int* __restrict__ slots,
    const float* __restrict__ slot_w,
    float* __restrict__ out)
{
    int e = blockIdx.z >> 1;
    int ks = blockIdx.z & 1;
    int cnt = counts[e];
    int m0 = blockIdx.y * 128;
    if (m0 >= cnt) return;
    int n0 = blockIdx.x * 64;

    __shared__ unsigned short As[128 * 32];
    __shared__ unsigned short Bs[64 * 32];
    __shared__ int sl[128];

    int t = threadIdx.x;
    int lane = t & 63, w = t >> 6;
    if (t < 128) {
        int r = m0 + t;
        sl[t] = slots[e * S + (r < cnt ? r : cnt - 1)];
    }
    __syncthreads();

    int quad = lane >> 4, l16 = lane & 15;
    int wm = (w >> 1) * 64, wn = (w & 1) * 32;

    int ar0 = w * 32 + (lane >> 2);
    int ar1 = ar0 + 16;
    int kbase = ks * (INTER / 2);
    const unsigned short* ap0 = act + (size_t)sl[ar0] * INTER + kbase + (lane & 3) * 8;
    const unsigned short* ap1 = act + (size_t)sl[ar1] * INTER + kbase + (lane & 3) * 8;
    int bn = w * 16 + (lane >> 2);
    // k-blocked: [e][kb][n][32]; start at kb = kbase/32 -> offset kbase*H
    const unsigned short* bp = dw + (size_t)e * H * INTER + (size_t)kbase * H + (size_t)(n0 + bn) * 32 + (lane & 3) * 8;

    unsigned short* la0 = &As[(2 * w) * 512 + lane * 8];
    unsigned short* la1 = &As[(2 * w + 1) * 512 + lane * 8];
    unsigned short* lb = &Bs[w * 512 + lane * 8];

    f32x4 acc[4][2];
#pragma unroll
    for (int mi = 0; mi < 4; ++mi)
#pragma unroll
        for (int ni = 0; ni < 2; ++ni)
            acc[mi][ni] = (f32x4){0.f, 0.f, 0.f, 0.f};

    for (int k0 = 0; k0 < INTER / 2; k0 += 32) {
        __syncthreads();
        gload16(ap0 + k0, la0);
        gload16(ap1 + k0, la1);
        gload16(bp + (size_t)k0 * H, lb);
        __syncthreads();
        bf16x8 af[4], bf[2];
#pragma unroll
        for (int mi = 0; mi < 4; ++mi)
            af[mi] = *(const bf16x8*)&As[(wm + mi * 16 + l16) * 32 + quad * 8];
#pragma unroll
        for (int ni = 0; ni < 2; ++ni)
            bf[ni] = *(const bf16x8*)&Bs[(wn + ni * 16 + l16) * 32 + quad * 8];
#pragma unroll
        for (int mi = 0; mi < 4; ++mi)
#pragma unroll
            for (int ni = 0; ni < 2; ++ni)
                acc[mi][ni] = __builtin_amdgcn_mfma_f32_16x16x32_bf16(af[mi], bf[ni], acc[mi][ni], 0, 0, 0);
    }

    const float* dbr = db + (size_t)e * H;
#pragma unroll
    for (int mi = 0; mi < 4; ++mi) {
#pragma unroll
        for (int r = 0; r < 4; ++r) {
            int rt = wm + mi * 16 + quad * 4 + r;
            if (m0 + rt >= cnt) continue;
            int slot = sl[rt];
            int tok = slot >> 1;
            float wgt = slot_w[slot];
#pragma unroll
            for (int ni = 0; ni < 2; ++ni) {
                int col = n0 + wn + ni * 16 + l16;
                float rr = acc[mi][ni][r] + (ks == 0 ? dbr[col] : 0.f);
                atomicAdd(&out[(size_t)tok * H + col], wgt * rr);
            }
        }
    }
}

// ---------------------------------------------------------------------------
extern "C" void kernel_launch(void* const* d_in, const int* in_sizes, int n_in,
                              void* d_out, int out_size, void* d_ws, size_t ws_size,
                              hipStream_t stream)
{
    const float* x   = (const float*)d_in[0];
    const float* rw  = (const float*)d_in[1];
    const float* rb  = (const float*)d_in[2];
    const float* gup = (const float*)d_in[3];
    const float* gub = (const float*)d_in[4];
    const float* dp  = (const float*)d_in[5];
    const float* db  = (const float*)d_in[6];
    float* out = (float*)d_out;

    char* ws = (char*)d_ws;
    int* counts            = (int*)(ws + WS_COUNTS);
    int* slots             = (int*)(ws + WS_SLOTS);
    float* slot_w          = (float*)(ws + WS_W);
    unsigned short* xb     = (unsigned short*)(ws + WS_XB);
    unsigned short* gw     = (unsigned short*)(ws + WS_GUP);
    unsigned short* dw     = (unsigned short*)(ws + WS_DPN);
    unsigned short* act    = (unsigned short*)(ws + WS_ACT);

    hipMemsetAsync(counts, 0, 4096, stream);
    hipMemsetAsync(out, 0, (size_t)S * H * sizeof(float), stream);

    router_conv<<<S, 64, 0, stream>>>(x, rw, rb, counts, slots, slot_w, xb);

    // balanced streaming repack: 1024 gate/up + 512 down blocks, equal work
    prep<<<NE * 128 + NE * 64, 256, 0, stream>>>(gup, dp, gw, dw);

    gateup_mfma<<<dim3(INTER / 64, 16, NE), 256, 0, stream>>>(
        xb, gw, gub, counts, slots, act);

    down_mfma<<<dim3(H / 64, 16, NE * 2), 256, 0, stream>>>(
        act, dw, db, counts, slots, slot_w, out);
}

// Round 15
// 438.837 us; speedup vs baseline: 1.0833x; 1.0468x over previous
//
#include <hip/hip_runtime.h>
#include <hip/hip_bf16.h>
#include <math.h>

// Problem constants
#define S 2048
#define H 1024
#define NE 8
#define INTER 2048
#define ALPHA 1.702f
#define LIMIT 7.0f

typedef __bf16 bf16x8 __attribute__((ext_vector_type(8)));
typedef float f32x4 __attribute__((ext_vector_type(4)));

// Workspace layout (bytes) -- prep/gw/dw eliminated: GEMMs consume fp32
// weights directly (saves 192 MB of HBM movement + the ~108us prep dispatch).
#define WS_COUNTS 0                                   // 4 KB
#define WS_SLOTS  4096                                // int[NE][S] = 64 KB
#define WS_W      (WS_SLOTS + NE*S*4)                 // float[2S] = 16 KB
#define WS_XB     (WS_W + 2*S*4)                      // bf16 x [S][H] = 4 MB
#define WS_ACT    (WS_XB + (size_t)S*H*2)             // bf16 [2S][I] = 16 MB

static __device__ __forceinline__ unsigned short f2bf(float f) {
    union { __hip_bfloat16 h; unsigned short u; } cv;
    cv.h = __float2bfloat16(f);
    return cv.u;
}

static __device__ __forceinline__ void gload16(const void* g, void* l) {
    __builtin_amdgcn_global_load_lds(
        (const __attribute__((address_space(1))) unsigned int*)(unsigned long long)g,
        (__attribute__((address_space(3))) unsigned int*)(unsigned int)(unsigned long long)l,
        16, 0, 0);
}

// ---------------------------------------------------------------------------
// Router + x->bf16 conversion. One wave per token.
// ---------------------------------------------------------------------------
__global__ __launch_bounds__(64) void router_conv(
    const float* __restrict__ x, const float* __restrict__ rw,
    const float* __restrict__ rb, int* __restrict__ counts,
    int* __restrict__ slots, float* __restrict__ slot_w,
    unsigned short* __restrict__ xb)
{
    int tok = blockIdx.x;
    int lane = threadIdx.x;
    const float4* xr = (const float4*)(x + (size_t)tok * H);
    ushort4* xo = (ushort4*)(xb + (size_t)tok * H);
    float acc[NE];
#pragma unroll
    for (int e = 0; e < NE; ++e) acc[e] = 0.f;
#pragma unroll
    for (int p = 0; p < H / 256; ++p) {
        int idx = p * 64 + lane;
        float4 v = xr[idx];
        ushort4 o;
        o.x = f2bf(v.x); o.y = f2bf(v.y); o.z = f2bf(v.z); o.w = f2bf(v.w);
        xo[idx] = o;
        const float* wr = rw + (size_t)idx * 4 * NE;
#pragma unroll
        for (int e = 0; e < NE; ++e)
            acc[e] += v.x * wr[e] + v.y * wr[NE + e] + v.z * wr[2 * NE + e] + v.w * wr[3 * NE + e];
    }
#pragma unroll
    for (int e = 0; e < NE; ++e) {
#pragma unroll
        for (int off = 32; off > 0; off >>= 1)
            acc[e] += __shfl_down(acc[e], off);
    }
    if (lane == 0) {
        float v[NE];
#pragma unroll
        for (int e = 0; e < NE; ++e) v[e] = acc[e] + rb[e];
        int i1 = 0; float v1 = v[0];
#pragma unroll
        for (int e = 1; e < NE; ++e) if (v[e] > v1) { v1 = v[e]; i1 = e; }
        int i2 = -1; float v2 = -3.0e38f;
#pragma unroll
        for (int e = 0; e < NE; ++e) if (e != i1 && v[e] > v2) { v2 = v[e]; i2 = e; }
        float w1 = 1.f / (1.f + expf(v2 - v1));
        float w2 = 1.f - w1;
        int p1 = atomicAdd(&counts[i1], 1);
        slots[i1 * S + p1] = tok * 2;
        slot_w[tok * 2] = w1;
        int p2 = atomicAdd(&counts[i2], 1);
        slots[i2 * S + p2] = tok * 2 + 1;
        slot_w[tok * 2 + 1] = w2;
    }
}

// ---------------------------------------------------------------------------
// Grouped gate_up MFMA GEMM, fp32 weights consumed DIRECTLY (no prep pass).
// Tile M=128 x N=64 (gate+up), BK=32, 4 waves 2x2.
// B staging: fp32 [32k][64n] tiles via gload16 (linear LDS, async);
// B fragments: 8x ds_read_b32 from the [k][n] tile (k = quad*8+i, n fixed
// per lane) + cvt to bf16 in regs. ~4-way bank conflict accepted (1.58x on
// those reads, m136); conversion is RNE -> numerics identical to prep path.
// Reads 128 MB fp32 weights instead of 64 MB bf16, but deletes prep's
// 192R+96W entirely: net -192 MB total HBM movement.
// ---------------------------------------------------------------------------
__global__ __launch_bounds__(256) void gateup_mfma(
    const unsigned short* __restrict__ xb,
    const float* __restrict__ gup,
    const float* __restrict__ gub,
    const int* __restrict__ counts, const int* __restrict__ slots,
    unsigned short* __restrict__ act)
{
    int e = blockIdx.z;
    int cnt = counts[e];
    int m0 = blockIdx.y * 128;
    if (m0 >= cnt) return;
    int n0 = blockIdx.x * 64;   // inter-col base (gate col n0; up col INTER+n0)

    __shared__ unsigned short As[128 * 32];   // bf16 [128m][32k]
    __shared__ float Gs[32][64];              // fp32 [32k][64n] gate tile
    __shared__ float Us[32][64];              // fp32 [32k][64n] up tile
    __shared__ int sl[128];

    int t = threadIdx.x;
    int lane = t & 63, w = t >> 6;
    if (t < 128) {
        int r = m0 + t;
        sl[t] = slots[e * S + (r < cnt ? r : cnt - 1)];
    }
    __syncthreads();

    int quad = lane >> 4, l16 = lane & 15;
    int wm = (w >> 1) * 64, wn = (w & 1) * 32;

    // A staging (bf16 tokens, unchanged)
    int ar0 = w * 32 + (lane >> 2);
    int ar1 = ar0 + 16;
    const unsigned short* ap0 = xb + (size_t)(sl[ar0] >> 1) * H + (lane & 3) * 8;
    const unsigned short* ap1 = xb + (size_t)(sl[ar1] >> 1) * H + (lane & 3) * 8;
    unsigned short* la0 = &As[(2 * w) * 512 + lane * 8];
    unsigned short* la1 = &As[(2 * w + 1) * 512 + lane * 8];

    // B staging: thread t covers (row = t>>4 [+16 for pass 1], colgrp = t&15).
    // LDS dest is linear in t (t*16 bytes) => gload16-compatible.
    int brow = t >> 4;              // 0..15
    int bcol = (t & 15) * 4;        // fp32 col
    const float* gsrc = gup + (size_t)e * H * 2 * INTER
                      + (size_t)brow * (2 * INTER) + n0 + bcol;
    const float* usrc = gsrc + INTER;
    float* lg = &Gs[brow][bcol];
    float* lu = &Us[brow][bcol];
    const size_t rs16 = (size_t)16 * 2 * INTER;   // +16 rows in global

    f32x4 accg[4][2], accu[4][2];
#pragma unroll
    for (int mi = 0; mi < 4; ++mi)
#pragma unroll
        for (int ni = 0; ni < 2; ++ni) {
            accg[mi][ni] = (f32x4){0.f, 0.f, 0.f, 0.f};
            accu[mi][ni] = (f32x4){0.f, 0.f, 0.f, 0.f};
        }

    for (int k0 = 0; k0 < H; k0 += 32) {
        __syncthreads();
        gload16(ap0 + k0, la0);
        gload16(ap1 + k0, la1);
        const float* gk = gsrc + (size_t)k0 * 2 * INTER;
        const float* uk = usrc + (size_t)k0 * 2 * INTER;
        gload16(gk, lg);
        gload16(gk + rs16, (char*)lg + 4096);
        gload16(uk, lu);
        gload16(uk + rs16, (char*)lu + 4096);
        __syncthreads();

        bf16x8 af[4], gf[2], uf[2];
#pragma unroll
        for (int mi = 0; mi < 4; ++mi)
            af[mi] = *(const bf16x8*)&As[(wm + mi * 16 + l16) * 32 + quad * 8];
#pragma unroll
        for (int ni = 0; ni < 2; ++ni) {
            int n = wn + ni * 16 + l16;
            union { bf16x8 v; __bf16 e[8]; } ug, uu;
#pragma unroll
            for (int i = 0; i < 8; ++i) {
                ug.e[i] = (__bf16)Gs[quad * 8 + i][n];
                uu.e[i] = (__bf16)Us[quad * 8 + i][n];
            }
            gf[ni] = ug.v;
            uf[ni] = uu.v;
        }
#pragma unroll
        for (int mi = 0; mi < 4; ++mi)
#pragma unroll
            for (int ni = 0; ni < 2; ++ni) {
                accg[mi][ni] = __builtin_amdgcn_mfma_f32_16x16x32_bf16(af[mi], gf[ni], accg[mi][ni], 0, 0, 0);
                accu[mi][ni] = __builtin_amdgcn_mfma_f32_16x16x32_bf16(af[mi], uf[ni], accu[mi][ni], 0, 0, 0);
            }
    }

    const float* gb = gub + (size_t)e * 2 * INTER;
#pragma unroll
    for (int mi = 0; mi < 4; ++mi) {
#pragma unroll
        for (int r = 0; r < 4; ++r) {
            int rt = wm + mi * 16 + quad * 4 + r;
            if (m0 + rt >= cnt) continue;
            int slot = sl[rt];
            unsigned short* orow = act + (size_t)slot * INTER;
#pragma unroll
            for (int ni = 0; ni < 2; ++ni) {
                int col = n0 + wn + ni * 16 + l16;
                float gate = accg[mi][ni][r] + gb[col];
                float uv = accu[mi][ni][r] + gb[INTER + col];
                gate = fminf(gate, LIMIT);
                uv = fminf(fmaxf(uv, -LIMIT), LIMIT);
                float glu = gate / (1.f + __expf(-ALPHA * gate));
                orow[col] = f2bf((uv + 1.f) * glu);
            }
        }
    }
}

// ---------------------------------------------------------------------------
// Grouped down MFMA GEMM, fp32 weights consumed directly. K-split 2.
// Same fp32 B-staging pattern as gateup (tile [32k][64n] from dp[e][I][H]).
// ---------------------------------------------------------------------------
__global__ __launch_bounds__(256) void down_mfma(
    const unsigned short* __restrict__ act,
    const float* __restrict__ dp,
    const float* __restrict__ db,
    const int* __restrict__ counts, const int* __restrict__ slots,
    const float* __restrict__ slot_w,
    float* __restrict__ out)
{
    int e = blockIdx.z >> 1;
    int ks = blockIdx.z & 1;
    int cnt = counts[e];
    int m0 = blockIdx.y * 128;
    if (m0 >= cnt) return;
    int n0 = blockIdx.x * 64;

    __shared__ unsigned short As[128 * 32];   // bf16 [128m][32k]
    __shared__ float Bs[32][64];              // fp32 [32k][64n]
    __shared__ int sl[128];

    int t = threadIdx.x;
    int lane = t & 63, w = t >> 6;
    if (t < 128) {
        int r = m0 + t;
        sl[t] = slots[e * S + (r < cnt ? r : cnt - 1)];
    }
    __syncthreads();

    int quad = lane >> 4, l16 = lane & 15;
    int wm = (w >> 1) * 64, wn = (w & 1) * 32;

    int ar0 = w * 32 + (lane >> 2);
    int ar1 = ar0 + 16;
    int kbase = ks * (INTER / 2);
    const unsigned short* ap0 = act + (size_t)sl[ar0] * INTER + kbase + (lane & 3) * 8;
    const unsigned short* ap1 = act + (size_t)sl[ar1] * INTER + kbase + (lane & 3) * 8;
    unsigned short* la0 = &As[(2 * w) * 512 + lane * 8];
    unsigned short* la1 = &As[(2 * w + 1) * 512 + lane * 8];

    int brow = t >> 4;
    int bcol = (t & 15) * 4;
    const float* bsrc = dp + (size_t)e * INTER * H
                      + (size_t)(kbase + brow) * H + n0 + bcol;
    float* lb = &Bs[brow][bcol];
    const size_t rs16 = (size_t)16 * H;

    f32x4 acc[4][2];
#pragma unroll
    for (int mi = 0; mi < 4; ++mi)
#pragma unroll
        for (int ni = 0; ni < 2; ++ni)
            acc[mi][ni] = (f32x4){0.f, 0.f, 0.f, 0.f};

    for (int k0 = 0; k0 < INTER / 2; k0 += 32) {
        __syncthreads();
        gload16(ap0 + k0, la0);
        gload16(ap1 + k0, la1);
        const float* bk = bsrc + (size_t)k0 * H;
        gload16(bk, lb);
        gload16(bk + rs16, (char*)lb + 4096);
        __syncthreads();

        bf16x8 af[4], bf[2];
#pragma unroll
        for (int mi = 0; mi < 4; ++mi)
            af[mi] = *(const bf16x8*)&As[(wm + mi * 16 + l16) * 32 + quad * 8];
#pragma unroll
        for (int ni = 0; ni < 2; ++ni) {
            int n = wn + ni * 16 + l16;
            union { bf16x8 v; __bf16 e[8]; } ub;
#pragma unroll
            for (int i = 0; i < 8; ++i)
                ub.e[i] = (__bf16)Bs[quad * 8 + i][n];
            bf[ni] = ub.v;
        }
#pragma unroll
        for (int mi = 0; mi < 4; ++mi)
#pragma unroll
            for (int ni = 0; ni < 2; ++ni)
                acc[mi][ni] = __builtin_amdgcn_mfma_f32_16x16x32_bf16(af[mi], bf[ni], acc[mi][ni], 0, 0, 0);
    }

    const float* dbr = db + (size_t)e * H;
#pragma unroll
    for (int mi = 0; mi < 4; ++mi) {
#pragma unroll
        for (int r = 0; r < 4; ++r) {
            int rt = wm + mi * 16 + quad * 4 + r;
            if (m0 + rt >= cnt) continue;
            int slot = sl[rt];
            int tok = slot >> 1;
            float wgt = slot_w[slot];
#pragma unroll
            for (int ni = 0; ni < 2; ++ni) {
                int col = n0 + wn + ni * 16 + l16;
                float rr = acc[mi][ni][r] + (ks == 0 ? dbr[col] : 0.f);
                atomicAdd(&out[(size_t)tok * H + col], wgt * rr);
            }
        }
    }
}

// ---------------------------------------------------------------------------
extern "C" void kernel_launch(void* const* d_in, const int* in_sizes, int n_in,
                              void* d_out, int out_size, void* d_ws, size_t ws_size,
                              hipStream_t stream)
{
    const float* x   = (const float*)d_in[0];
    const float* rw  = (const float*)d_in[1];
    const float* rb  = (const float*)d_in[2];
    const float* gup = (const float*)d_in[3];
    const float* gub = (const float*)d_in[4];
    const float* dp  = (const float*)d_in[5];
    const float* db  = (const float*)d_in[6];
    float* out = (float*)d_out;

    char* ws = (char*)d_ws;
    int* counts            = (int*)(ws + WS_COUNTS);
    int* slots             = (int*)(ws + WS_SLOTS);
    float* slot_w          = (float*)(ws + WS_W);
    unsigned short* xb     = (unsigned short*)(ws + WS_XB);
    unsigned short* act    = (unsigned short*)(ws + WS_ACT);

    hipMemsetAsync(counts, 0, 4096, stream);
    hipMemsetAsync(out, 0, (size_t)S * H * sizeof(float), stream);

    router_conv<<<S, 64, 0, stream>>>(x, rw, rb, counts, slots, slot_w, xb);

    gateup_mfma<<<dim3(INTER / 64, 16, NE), 256, 0, stream>>>(
        xb, gup, gub, counts, slots, act);

    down_mfma<<<dim3(H / 64, 16, NE * 2), 256, 0, stream>>>(
        act, dp, db, counts, slots, slot_w, out);
}